// Round 12
// baseline (537.183 us; speedup 1.0000x reference)
//
#include <hip/hip_runtime.h>
#include <math.h>

namespace {

constexpr int N = 50000;
constexpr int E = 400000;
constexpr int G = 64;
constexpr int HID = 64;
constexpr int HH = 256; // NHEAD*HID
constexpr float NEG = 0.2f;
constexpr int EP = E + 3 * N; // max padded CSR entries

// ---- degree histogram + per-edge rank (deg pre-zeroed by memset) ----
__global__ __launch_bounds__(256) void hist_k(
    const int* __restrict__ dst, int* __restrict__ deg, int* __restrict__ rank)
{
    int e = blockIdx.x * 256 + threadIdx.x;
    if (e < E) rank[e] = atomicAdd(&deg[dst[e]], 1);
}

// scan over PADDED degrees: pdeg = (deg+3)&~3
__global__ __launch_bounds__(256) void scan1_k(
    const int* __restrict__ deg, int* __restrict__ pre, int* __restrict__ bsum)
{
    __shared__ int s[256];
    int i = blockIdx.x * 256 + threadIdx.x;
    int v = (i < N) ? ((deg[i] + 3) & ~3) : 0;
    s[threadIdx.x] = v;
    __syncthreads();
    for (int off = 1; off < 256; off <<= 1) {
        int t = (threadIdx.x >= off) ? s[threadIdx.x - off] : 0;
        __syncthreads();
        s[threadIdx.x] += t;
        __syncthreads();
    }
    if (i < N) pre[i] = s[threadIdx.x] - v;
    if (threadIdx.x == 255) bsum[blockIdx.x] = s[255];
}

__global__ __launch_bounds__(256) void scan2_k(int* __restrict__ bsum, int nb)
{
    __shared__ int s[256];
    int tid = threadIdx.x;
    int v = (tid < nb) ? bsum[tid] : 0;
    s[tid] = v;
    __syncthreads();
    for (int off = 1; off < 256; off <<= 1) {
        int t = (tid >= off) ? s[tid - off] : 0;
        __syncthreads();
        s[tid] += t;
        __syncthreads();
    }
    if (tid < nb) bsum[tid] = s[tid] - v;
}

__global__ __launch_bounds__(256) void scan3_k(
    int* __restrict__ pre, const int* __restrict__ bsum)
{
    int i = blockIdx.x * 256 + threadIdx.x;
    if (i >= N) return;
    pre[i] += bsum[blockIdx.x];
}

// ---- scatter edges to padded CSR (no atomics); compute eap on the fly ----
// pad slots keep csr_src = -1 (memset 0xFF) and are masked in gat_aggr.
__global__ __launch_bounds__(256) void scatter_k(
    const int* __restrict__ src, const int* __restrict__ dst,
    const float* __restrict__ ea,
    const float* __restrict__ W_et, const float* __restrict__ b_et,
    const float* __restrict__ W_uw, const float* __restrict__ b_uw,
    const float* __restrict__ W_ua, const float* __restrict__ b_ua,
    const int* __restrict__ row_start, const int* __restrict__ rank,
    int* __restrict__ csr_src, float* __restrict__ eap_csr)
{
    int e = blockIdx.x * 256 + threadIdx.x;
    if (e >= E) return;
    float et = ea[e * 2 + 0], uw = ea[e * 2 + 1];
    float ua = 1.f / (1.f + expf(-(uw * W_ua[0] + b_ua[0])));
    float4 v;
    v.x = et * W_et[0] + b_et[0];
    v.y = et * W_et[1] + b_et[1];
    v.z = (uw * W_uw[0] + b_uw[0]) * ua;
    v.w = (uw * W_uw[1] + b_uw[1]) * ua;
    int pos = row_start[dst[e]] + rank[e];
    csr_src[pos] = src[e];
    *(float4*)&eap_csr[(size_t)pos * 4] = v;
}

// ---- node projection (round-6 best): 32 nodes/block LDS, 4 cols x 8 nodes ----
template <int IC>
__global__ __launch_bounds__(256) void proj_k(
    const float* __restrict__ x,
    const float* __restrict__ Wl, const float* __restrict__ bl,
    const float* __restrict__ Wr, const float* __restrict__ br,
    float* __restrict__ xl, float* __restrict__ xr)
{
    constexpr int NPB = 32;
    __shared__ float xs[NPB][IC];
    const float* __restrict__ W  = blockIdx.y ? Wr : Wl;
    const float* __restrict__ bp = blockIdx.y ? br : bl;
    float* __restrict__ out      = blockIdx.y ? xr : xl;
    const int base = blockIdx.x * NPB;
    const int tid = threadIdx.x;
    for (int idx = tid; idx < NPB * IC / 4; idx += 256) {
        int j = idx / (IC / 4), k4 = idx - j * (IC / 4);
        int n = base + j;
        float4 v = make_float4(0.f, 0.f, 0.f, 0.f);
        if (n < N) v = *(const float4*)&x[(size_t)n * IC + k4 * 4];
        *(float4*)&xs[j][k4 * 4] = v;
    }
    __syncthreads();
    const int col4 = (tid & 63) * 4;
    const int jg = (tid >> 6) * 8;   // 8 nodes per thread
    float4 acc[8];
#pragma unroll
    for (int j = 0; j < 8; j++) acc[j] = make_float4(0.f, 0.f, 0.f, 0.f);
    for (int k = 0; k < IC; k += 4) {
        float4 w0 = *(const float4*)&W[(size_t)(k + 0) * HH + col4];
        float4 w1 = *(const float4*)&W[(size_t)(k + 1) * HH + col4];
        float4 w2 = *(const float4*)&W[(size_t)(k + 2) * HH + col4];
        float4 w3 = *(const float4*)&W[(size_t)(k + 3) * HH + col4];
#pragma unroll
        for (int j = 0; j < 8; j++) {
            float4 xv = *(const float4*)&xs[jg + j][k];
            acc[j].x += xv.x * w0.x + xv.y * w1.x + xv.z * w2.x + xv.w * w3.x;
            acc[j].y += xv.x * w0.y + xv.y * w1.y + xv.z * w2.y + xv.w * w3.y;
            acc[j].z += xv.x * w0.z + xv.y * w1.z + xv.z * w2.z + xv.w * w3.z;
            acc[j].w += xv.x * w0.w + xv.y * w1.w + xv.z * w2.w + xv.w * w3.w;
        }
    }
    float4 bb = *(const float4*)&bp[col4];
#pragma unroll
    for (int j = 0; j < 8; j++) {
        int n = base + jg + j;
        if (n < N) {
            float4 o;
            o.x = acc[j].x + bb.x;
            o.y = acc[j].y + bb.y;
            o.z = acc[j].z + bb.z;
            o.w = acc[j].w + bb.w;
            *(float4*)&out[(size_t)n * HH + col4] = o;
        }
    }
}

// ---- fused GAT layer: unroll-4 over padded rows (no tail loop) ----
// one 64-lane wave per dst node; lane l covers cols 4l..4l+3 (head = l>>4)
__global__ __launch_bounds__(256) void gat_aggr_k(
    const float* __restrict__ xl, const float* __restrict__ xr,
    const float* __restrict__ eap_csr, const float* __restrict__ We,
    const float* __restrict__ att,
    const int* __restrict__ row_start, const int* __restrict__ deg,
    const int* __restrict__ csr_src,
    const float* __restrict__ bias, float* __restrict__ hout)
{
    int d = blockIdx.x * 4 + (threadIdx.x >> 6);
    int lane = threadIdx.x & 63;
    if (d >= N) return;
    int c4 = lane * 4;
    const float4 w0 = *(const float4*)&We[0 * HH + c4];
    const float4 w1 = *(const float4*)&We[1 * HH + c4];
    const float4 w2 = *(const float4*)&We[2 * HH + c4];
    const float4 w3 = *(const float4*)&We[3 * HH + c4];
    const float4 av = *(const float4*)&att[c4];
    const float4 vr = *(const float4*)&xr[(size_t)d * HH + c4];
    int start = row_start[d];
    int end = start + ((deg[d] + 3) & ~3);  // padded row length
    float m = -INFINITY, denom = 0.f;
    float ax = 0.f, ay = 0.f, az = 0.f, aw = 0.f;
    for (int idx = start; idx < end; idx += 4) {
        int s0 = csr_src[idx], s1 = csr_src[idx + 1];
        int s2 = csr_src[idx + 2], s3 = csr_src[idx + 3];
        int t0 = (s0 < 0) ? 0 : s0;
        int t1 = (s1 < 0) ? 0 : s1;
        int t2 = (s2 < 0) ? 0 : s2;
        int t3 = (s3 < 0) ? 0 : s3;
        float4 a0 = *(const float4*)&eap_csr[(size_t)(idx + 0) * 4];
        float4 a1 = *(const float4*)&eap_csr[(size_t)(idx + 1) * 4];
        float4 a2 = *(const float4*)&eap_csr[(size_t)(idx + 2) * 4];
        float4 a3 = *(const float4*)&eap_csr[(size_t)(idx + 3) * 4];
        float4 vl0 = *(const float4*)&xl[(size_t)t0 * HH + c4];
        float4 vl1 = *(const float4*)&xl[(size_t)t1 * HH + c4];
        float4 vl2 = *(const float4*)&xl[(size_t)t2 * HH + c4];
        float4 vl3 = *(const float4*)&xl[(size_t)t3 * HH + c4];
        float p0, p1, p2, p3;
        {
            float q0 = vl0.x + vr.x + a0.x * w0.x + a0.y * w1.x + a0.z * w2.x + a0.w * w3.x;
            float q1 = vl0.y + vr.y + a0.x * w0.y + a0.y * w1.y + a0.z * w2.y + a0.w * w3.y;
            float q2 = vl0.z + vr.z + a0.x * w0.z + a0.y * w1.z + a0.z * w2.z + a0.w * w3.z;
            float q3 = vl0.w + vr.w + a0.x * w0.w + a0.y * w1.w + a0.z * w2.w + a0.w * w3.w;
            q0 = (q0 > 0.f) ? q0 : NEG * q0; q1 = (q1 > 0.f) ? q1 : NEG * q1;
            q2 = (q2 > 0.f) ? q2 : NEG * q2; q3 = (q3 > 0.f) ? q3 : NEG * q3;
            p0 = q0 * av.x + q1 * av.y + q2 * av.z + q3 * av.w;
        }
        {
            float q0 = vl1.x + vr.x + a1.x * w0.x + a1.y * w1.x + a1.z * w2.x + a1.w * w3.x;
            float q1 = vl1.y + vr.y + a1.x * w0.y + a1.y * w1.y + a1.z * w2.y + a1.w * w3.y;
            float q2 = vl1.z + vr.z + a1.x * w0.z + a1.y * w1.z + a1.z * w2.z + a1.w * w3.z;
            float q3 = vl1.w + vr.w + a1.x * w0.w + a1.y * w1.w + a1.z * w2.w + a1.w * w3.w;
            q0 = (q0 > 0.f) ? q0 : NEG * q0; q1 = (q1 > 0.f) ? q1 : NEG * q1;
            q2 = (q2 > 0.f) ? q2 : NEG * q2; q3 = (q3 > 0.f) ? q3 : NEG * q3;
            p1 = q0 * av.x + q1 * av.y + q2 * av.z + q3 * av.w;
        }
        {
            float q0 = vl2.x + vr.x + a2.x * w0.x + a2.y * w1.x + a2.z * w2.x + a2.w * w3.x;
            float q1 = vl2.y + vr.y + a2.x * w0.y + a2.y * w1.y + a2.z * w2.y + a2.w * w3.y;
            float q2 = vl2.z + vr.z + a2.x * w0.z + a2.y * w1.z + a2.z * w2.z + a2.w * w3.z;
            float q3 = vl2.w + vr.w + a2.x * w0.w + a2.y * w1.w + a2.z * w2.w + a2.w * w3.w;
            q0 = (q0 > 0.f) ? q0 : NEG * q0; q1 = (q1 > 0.f) ? q1 : NEG * q1;
            q2 = (q2 > 0.f) ? q2 : NEG * q2; q3 = (q3 > 0.f) ? q3 : NEG * q3;
            p2 = q0 * av.x + q1 * av.y + q2 * av.z + q3 * av.w;
        }
        {
            float q0 = vl3.x + vr.x + a3.x * w0.x + a3.y * w1.x + a3.z * w2.x + a3.w * w3.x;
            float q1 = vl3.y + vr.y + a3.x * w0.y + a3.y * w1.y + a3.z * w2.y + a3.w * w3.y;
            float q2 = vl3.z + vr.z + a3.x * w0.z + a3.y * w1.z + a3.z * w2.z + a3.w * w3.z;
            float q3 = vl3.w + vr.w + a3.x * w0.w + a3.y * w1.w + a3.z * w2.w + a3.w * w3.w;
            q0 = (q0 > 0.f) ? q0 : NEG * q0; q1 = (q1 > 0.f) ? q1 : NEG * q1;
            q2 = (q2 > 0.f) ? q2 : NEG * q2; q3 = (q3 > 0.f) ? q3 : NEG * q3;
            p3 = q0 * av.x + q1 * av.y + q2 * av.z + q3 * av.w;
        }
#pragma unroll
        for (int off = 1; off <= 8; off <<= 1) {
            p0 += __shfl_xor(p0, off, 64);
            p1 += __shfl_xor(p1, off, 64);
            p2 += __shfl_xor(p2, off, 64);
            p3 += __shfl_xor(p3, off, 64);
        }
        // mask pad slots to -inf -> exp()=0, softmax unchanged
        p0 = (s0 < 0) ? -INFINITY : p0;
        p1 = (s1 < 0) ? -INFINITY : p1;
        p2 = (s2 < 0) ? -INFINITY : p2;
        p3 = (s3 < 0) ? -INFINITY : p3;
        float pm = fmaxf(fmaxf(p0, p1), fmaxf(p2, p3));
        float newm = fmaxf(m, pm);
        float so = expf(m - newm);
        float e0 = expf(p0 - newm);
        float e1 = expf(p1 - newm);
        float e2 = expf(p2 - newm);
        float e3 = expf(p3 - newm);
        denom = denom * so + e0 + e1 + e2 + e3;
        ax = ax * so + e0 * vl0.x + e1 * vl1.x + e2 * vl2.x + e3 * vl3.x;
        ay = ay * so + e0 * vl0.y + e1 * vl1.y + e2 * vl2.y + e3 * vl3.y;
        az = az * so + e0 * vl0.z + e1 * vl1.z + e2 * vl2.z + e3 * vl3.z;
        aw = aw * so + e0 * vl0.w + e1 * vl1.w + e2 * vl2.w + e3 * vl3.w;
        m = newm;
    }
    float inv = 0.25f / (denom + 1e-16f);   // head-mean folded in
    ax *= inv; ay *= inv; az *= inv; aw *= inv;
    ax += __shfl_xor(ax, 16, 64); ax += __shfl_xor(ax, 32, 64);
    ay += __shfl_xor(ay, 16, 64); ay += __shfl_xor(ay, 32, 64);
    az += __shfl_xor(az, 16, 64); az += __shfl_xor(az, 32, 64);
    aw += __shfl_xor(aw, 16, 64); aw += __shfl_xor(aw, 32, 64);
    if (lane < 16) {
        float4 b = *(const float4*)&bias[c4];
        float4 o;
        o.x = fmaxf(ax + b.x, 0.f);
        o.y = fmaxf(ay + b.y, 0.f);
        o.z = fmaxf(az + b.z, 0.f);
        o.w = fmaxf(aw + b.w, 0.f);
        *(float4*)&hout[(size_t)d * HID + c4] = o;
    }
}

// ---- pooling + MLP head fused: one block (256 threads, 4 waves) per graph ----
__global__ __launch_bounds__(256) void head_k(
    const float* __restrict__ h, const int* __restrict__ batch,
    const float* __restrict__ W_fc, const float* __restrict__ b_fc,
    const float* __restrict__ W_res, const float* __restrict__ b_res,
    const float* __restrict__ W_time, const float* __restrict__ b_time,
    float* __restrict__ out)
{
    int g = blockIdx.x;
    int c = threadIdx.x & 63;
    int w = threadIdx.x >> 6;
    // batch is sorted: [start, end) for graph g
    int lo = 0, hi = N;
    while (lo < hi) { int mid = (lo + hi) >> 1; if (batch[mid] < g) lo = mid + 1; else hi = mid; }
    int start = lo;
    hi = N;
    while (lo < hi) { int mid = (lo + hi) >> 1; if (batch[mid] < g + 1) lo = mid + 1; else hi = mid; }
    int end = lo;
    float sum = 0.f;
    for (int n = start + w; n < end; n += 4) sum += h[(size_t)n * HID + c];
    __shared__ float red[4][HID];
    red[w][c] = sum;
    __syncthreads();
    __shared__ float ps[HID];
    if (w == 0) {
        float cnt = (float)(end - start);
        float p = (red[0][c] + red[1][c] + red[2][c] + red[3][c]) / fmaxf(cnt, 1.0f);
        ps[c] = p;
    }
    __syncthreads();
    if (w == 0) {
        float gv = b_fc[c];
        for (int k = 0; k < HID; k++) gv += ps[k] * W_fc[k * HID + c];
        gv = fmaxf(gv, 0.f);
        float r = gv * W_res[c];
        float t = gv * W_time[c];
#pragma unroll
        for (int off = 32; off > 0; off >>= 1) {
            r += __shfl_down(r, off, 64);
            t += __shfl_down(t, off, 64);
        }
        if (c == 0) {
            out[g * 2 + 0] = r + b_res[0];
            out[g * 2 + 1] = t + b_time[0];
        }
    }
}

} // namespace

extern "C" void kernel_launch(void* const* d_in, const int* in_sizes, int n_in,
                              void* d_out, int out_size, void* d_ws, size_t ws_size,
                              hipStream_t stream) {
    const float* x         = (const float*)d_in[0];
    const float* edge_attr = (const float*)d_in[1];
    const int*   edge_index= (const int*)d_in[2];
    const int*   batch     = (const int*)d_in[3];
    const float* W_et = (const float*)d_in[4];
    const float* b_et = (const float*)d_in[5];
    const float* W_uw = (const float*)d_in[6];
    const float* b_uw = (const float*)d_in[7];
    const float* W_ua = (const float*)d_in[8];
    const float* b_ua = (const float*)d_in[9];
    const float* Wl0  = (const float*)d_in[10];
    const float* bl0  = (const float*)d_in[11];
    const float* Wr0  = (const float*)d_in[12];
    const float* br0  = (const float*)d_in[13];
    const float* att0 = (const float*)d_in[14];
    const float* We0  = (const float*)d_in[15];
    const float* bias0= (const float*)d_in[16];
    const float* Wl1  = (const float*)d_in[17];
    const float* bl1  = (const float*)d_in[18];
    const float* Wr1  = (const float*)d_in[19];
    const float* br1  = (const float*)d_in[20];
    const float* att1 = (const float*)d_in[21];
    const float* We1  = (const float*)d_in[22];
    const float* bias1= (const float*)d_in[23];
    const float* W_fc = (const float*)d_in[24];
    const float* b_fc = (const float*)d_in[25];
    const float* W_res= (const float*)d_in[26];
    const float* b_res= (const float*)d_in[27];
    const float* W_time=(const float*)d_in[28];
    const float* b_time=(const float*)d_in[29];

    const int* src = edge_index;     // row 0
    const int* dst = edge_index + E; // row 1

    // workspace layout (16B aligned segments)
    float* ws    = (float*)d_ws;
    float* xl    = ws;                        // N*HH
    float* xr    = xl  + (size_t)N * HH;      // N*HH
    float* h1    = xr  + (size_t)N * HH;      // N*HID
    float* h2    = h1  + (size_t)N * HID;     // N*HID
    int*   deg      = (int*)(h2 + (size_t)N * HID); // N
    int*   row_start= deg + N;                // N
    int*   bsum     = row_start + N;          // 256
    int*   rank     = bsum + 256;             // E
    int*   csr_src  = rank + E;               // EP
    float* eap_csr  = (float*)(csr_src + EP); // EP*4

    dim3 b256(256);
    const int NB = (N + 255) / 256; // 196

    // deg = 0 ; csr_src = -1 (pad sentinel)
    hipMemsetAsync(deg, 0, (size_t)N * 4, stream);
    hipMemsetAsync(csr_src, 0xFF, (size_t)EP * 4, stream);
    // CSR build (rank-based, padded rows)
    hist_k<<<(E + 255) / 256, b256, 0, stream>>>(dst, deg, rank);
    scan1_k<<<NB, b256, 0, stream>>>(deg, row_start, bsum);
    scan2_k<<<1, b256, 0, stream>>>(bsum, NB);
    scan3_k<<<NB, b256, 0, stream>>>(row_start, bsum);
    scatter_k<<<(E + 255) / 256, b256, 0, stream>>>(
        src, dst, edge_attr, W_et, b_et, W_uw, b_uw, W_ua, b_ua,
        row_start, rank, csr_src, eap_csr);

    dim3 proj_grid((N + 31) / 32, 2);

    // ---------- layer 0 ----------
    proj_k<128><<<proj_grid, b256, 0, stream>>>(x, Wl0, bl0, Wr0, br0, xl, xr);
    gat_aggr_k<<<(N + 3) / 4, b256, 0, stream>>>(
        xl, xr, eap_csr, We0, att0, row_start, deg, csr_src, bias0, h1);

    // ---------- layer 1 ----------
    proj_k<64><<<proj_grid, b256, 0, stream>>>(h1, Wl1, bl1, Wr1, br1, xl, xr);
    gat_aggr_k<<<(N + 3) / 4, b256, 0, stream>>>(
        xl, xr, eap_csr, We1, att1, row_start, deg, csr_src, bias1, h2);

    // ---------- fused pooling + head ----------
    head_k<<<G, b256, 0, stream>>>(
        h2, batch, W_fc, b_fc, W_res, b_res, W_time, b_time, (float*)d_out);
}

// Round 13
// 501.687 us; speedup vs baseline: 1.0708x; 1.0708x over previous
//
#include <hip/hip_runtime.h>
#include <math.h>

namespace {

constexpr int N = 50000;
constexpr int E = 400000;
constexpr int G = 64;
constexpr int HID = 64;
constexpr int HH = 256; // NHEAD*HID
constexpr float NEG = 0.2f;
constexpr int EP = E + 3 * N; // max padded CSR entries

// ---- degree histogram + per-edge rank (deg pre-zeroed by memset) ----
__global__ __launch_bounds__(256) void hist_k(
    const int* __restrict__ dst, int* __restrict__ deg, int* __restrict__ rank)
{
    int e = blockIdx.x * 256 + threadIdx.x;
    if (e < E) rank[e] = atomicAdd(&deg[dst[e]], 1);
}

// scan over PADDED degrees: pdeg = (deg+3)&~3
__global__ __launch_bounds__(256) void scan1_k(
    const int* __restrict__ deg, int* __restrict__ pre, int* __restrict__ bsum)
{
    __shared__ int s[256];
    int i = blockIdx.x * 256 + threadIdx.x;
    int v = (i < N) ? ((deg[i] + 3) & ~3) : 0;
    s[threadIdx.x] = v;
    __syncthreads();
    for (int off = 1; off < 256; off <<= 1) {
        int t = (threadIdx.x >= off) ? s[threadIdx.x - off] : 0;
        __syncthreads();
        s[threadIdx.x] += t;
        __syncthreads();
    }
    if (i < N) pre[i] = s[threadIdx.x] - v;
    if (threadIdx.x == 255) bsum[blockIdx.x] = s[255];
}

__global__ __launch_bounds__(256) void scan2_k(int* __restrict__ bsum, int nb)
{
    __shared__ int s[256];
    int tid = threadIdx.x;
    int v = (tid < nb) ? bsum[tid] : 0;
    s[tid] = v;
    __syncthreads();
    for (int off = 1; off < 256; off <<= 1) {
        int t = (tid >= off) ? s[tid - off] : 0;
        __syncthreads();
        s[tid] += t;
        __syncthreads();
    }
    if (tid < nb) bsum[tid] = s[tid] - v;
}

__global__ __launch_bounds__(256) void scan3_k(
    int* __restrict__ pre, const int* __restrict__ bsum)
{
    int i = blockIdx.x * 256 + threadIdx.x;
    if (i >= N) return;
    pre[i] += bsum[blockIdx.x];
}

// ---- scatter edges to padded CSR (no atomics); compute eap on the fly ----
// pad slots keep csr_src = -1 (memset 0xFF) and are masked in gat_aggr.
__global__ __launch_bounds__(256) void scatter_k(
    const int* __restrict__ src, const int* __restrict__ dst,
    const float* __restrict__ ea,
    const float* __restrict__ W_et, const float* __restrict__ b_et,
    const float* __restrict__ W_uw, const float* __restrict__ b_uw,
    const float* __restrict__ W_ua, const float* __restrict__ b_ua,
    const int* __restrict__ row_start, const int* __restrict__ rank,
    int* __restrict__ csr_src, float* __restrict__ eap_csr)
{
    int e = blockIdx.x * 256 + threadIdx.x;
    if (e >= E) return;
    float et = ea[e * 2 + 0], uw = ea[e * 2 + 1];
    float ua = 1.f / (1.f + expf(-(uw * W_ua[0] + b_ua[0])));
    float4 v;
    v.x = et * W_et[0] + b_et[0];
    v.y = et * W_et[1] + b_et[1];
    v.z = (uw * W_uw[0] + b_uw[0]) * ua;
    v.w = (uw * W_uw[1] + b_uw[1]) * ua;
    int pos = row_start[dst[e]] + rank[e];
    csr_src[pos] = src[e];
    *(float4*)&eap_csr[(size_t)pos * 4] = v;
}

// ---- node projection (round-6 best): 32 nodes/block LDS, 4 cols x 8 nodes ----
template <int IC>
__global__ __launch_bounds__(256) void proj_k(
    const float* __restrict__ x,
    const float* __restrict__ Wl, const float* __restrict__ bl,
    const float* __restrict__ Wr, const float* __restrict__ br,
    float* __restrict__ xl, float* __restrict__ xr)
{
    constexpr int NPB = 32;
    __shared__ float xs[NPB][IC];
    const float* __restrict__ W  = blockIdx.y ? Wr : Wl;
    const float* __restrict__ bp = blockIdx.y ? br : bl;
    float* __restrict__ out      = blockIdx.y ? xr : xl;
    const int base = blockIdx.x * NPB;
    const int tid = threadIdx.x;
    for (int idx = tid; idx < NPB * IC / 4; idx += 256) {
        int j = idx / (IC / 4), k4 = idx - j * (IC / 4);
        int n = base + j;
        float4 v = make_float4(0.f, 0.f, 0.f, 0.f);
        if (n < N) v = *(const float4*)&x[(size_t)n * IC + k4 * 4];
        *(float4*)&xs[j][k4 * 4] = v;
    }
    __syncthreads();
    const int col4 = (tid & 63) * 4;
    const int jg = (tid >> 6) * 8;   // 8 nodes per thread
    float4 acc[8];
#pragma unroll
    for (int j = 0; j < 8; j++) acc[j] = make_float4(0.f, 0.f, 0.f, 0.f);
    for (int k = 0; k < IC; k += 4) {
        float4 w0 = *(const float4*)&W[(size_t)(k + 0) * HH + col4];
        float4 w1 = *(const float4*)&W[(size_t)(k + 1) * HH + col4];
        float4 w2 = *(const float4*)&W[(size_t)(k + 2) * HH + col4];
        float4 w3 = *(const float4*)&W[(size_t)(k + 3) * HH + col4];
#pragma unroll
        for (int j = 0; j < 8; j++) {
            float4 xv = *(const float4*)&xs[jg + j][k];
            acc[j].x += xv.x * w0.x + xv.y * w1.x + xv.z * w2.x + xv.w * w3.x;
            acc[j].y += xv.x * w0.y + xv.y * w1.y + xv.z * w2.y + xv.w * w3.y;
            acc[j].z += xv.x * w0.z + xv.y * w1.z + xv.z * w2.z + xv.w * w3.z;
            acc[j].w += xv.x * w0.w + xv.y * w1.w + xv.z * w2.w + xv.w * w3.w;
        }
    }
    float4 bb = *(const float4*)&bp[col4];
#pragma unroll
    for (int j = 0; j < 8; j++) {
        int n = base + jg + j;
        if (n < N) {
            float4 o;
            o.x = acc[j].x + bb.x;
            o.y = acc[j].y + bb.y;
            o.z = acc[j].z + bb.z;
            o.w = acc[j].w + bb.w;
            *(float4*)&out[(size_t)n * HH + col4] = o;
        }
    }
}

// ---- fused GAT layer: unroll-4 over padded rows (no tail loop) ----
// one 64-lane wave per dst node; lane l covers cols 4l..4l+3 (head = l>>4)
__global__ __launch_bounds__(256) void gat_aggr_k(
    const float* __restrict__ xl, const float* __restrict__ xr,
    const float* __restrict__ eap_csr, const float* __restrict__ We,
    const float* __restrict__ att,
    const int* __restrict__ row_start, const int* __restrict__ deg,
    const int* __restrict__ csr_src,
    const float* __restrict__ bias, float* __restrict__ hout)
{
    int d = blockIdx.x * 4 + (threadIdx.x >> 6);
    int lane = threadIdx.x & 63;
    if (d >= N) return;
    int c4 = lane * 4;
    const float4 w0 = *(const float4*)&We[0 * HH + c4];
    const float4 w1 = *(const float4*)&We[1 * HH + c4];
    const float4 w2 = *(const float4*)&We[2 * HH + c4];
    const float4 w3 = *(const float4*)&We[3 * HH + c4];
    const float4 av = *(const float4*)&att[c4];
    const float4 vr = *(const float4*)&xr[(size_t)d * HH + c4];
    int start = row_start[d];
    int end = start + ((deg[d] + 3) & ~3);  // padded row length
    float m = -INFINITY, denom = 0.f;
    float ax = 0.f, ay = 0.f, az = 0.f, aw = 0.f;
    for (int idx = start; idx < end; idx += 4) {
        int s0 = csr_src[idx], s1 = csr_src[idx + 1];
        int s2 = csr_src[idx + 2], s3 = csr_src[idx + 3];
        int t0 = (s0 < 0) ? 0 : s0;
        int t1 = (s1 < 0) ? 0 : s1;
        int t2 = (s2 < 0) ? 0 : s2;
        int t3 = (s3 < 0) ? 0 : s3;
        float4 a0 = *(const float4*)&eap_csr[(size_t)(idx + 0) * 4];
        float4 a1 = *(const float4*)&eap_csr[(size_t)(idx + 1) * 4];
        float4 a2 = *(const float4*)&eap_csr[(size_t)(idx + 2) * 4];
        float4 a3 = *(const float4*)&eap_csr[(size_t)(idx + 3) * 4];
        float4 vl0 = *(const float4*)&xl[(size_t)t0 * HH + c4];
        float4 vl1 = *(const float4*)&xl[(size_t)t1 * HH + c4];
        float4 vl2 = *(const float4*)&xl[(size_t)t2 * HH + c4];
        float4 vl3 = *(const float4*)&xl[(size_t)t3 * HH + c4];
        float p0, p1, p2, p3;
        {
            float q0 = vl0.x + vr.x + a0.x * w0.x + a0.y * w1.x + a0.z * w2.x + a0.w * w3.x;
            float q1 = vl0.y + vr.y + a0.x * w0.y + a0.y * w1.y + a0.z * w2.y + a0.w * w3.y;
            float q2 = vl0.z + vr.z + a0.x * w0.z + a0.y * w1.z + a0.z * w2.z + a0.w * w3.z;
            float q3 = vl0.w + vr.w + a0.x * w0.w + a0.y * w1.w + a0.z * w2.w + a0.w * w3.w;
            q0 = (q0 > 0.f) ? q0 : NEG * q0; q1 = (q1 > 0.f) ? q1 : NEG * q1;
            q2 = (q2 > 0.f) ? q2 : NEG * q2; q3 = (q3 > 0.f) ? q3 : NEG * q3;
            p0 = q0 * av.x + q1 * av.y + q2 * av.z + q3 * av.w;
        }
        {
            float q0 = vl1.x + vr.x + a1.x * w0.x + a1.y * w1.x + a1.z * w2.x + a1.w * w3.x;
            float q1 = vl1.y + vr.y + a1.x * w0.y + a1.y * w1.y + a1.z * w2.y + a1.w * w3.y;
            float q2 = vl1.z + vr.z + a1.x * w0.z + a1.y * w1.z + a1.z * w2.z + a1.w * w3.z;
            float q3 = vl1.w + vr.w + a1.x * w0.w + a1.y * w1.w + a1.z * w2.w + a1.w * w3.w;
            q0 = (q0 > 0.f) ? q0 : NEG * q0; q1 = (q1 > 0.f) ? q1 : NEG * q1;
            q2 = (q2 > 0.f) ? q2 : NEG * q2; q3 = (q3 > 0.f) ? q3 : NEG * q3;
            p1 = q0 * av.x + q1 * av.y + q2 * av.z + q3 * av.w;
        }
        {
            float q0 = vl2.x + vr.x + a2.x * w0.x + a2.y * w1.x + a2.z * w2.x + a2.w * w3.x;
            float q1 = vl2.y + vr.y + a2.x * w0.y + a2.y * w1.y + a2.z * w2.y + a2.w * w3.y;
            float q2 = vl2.z + vr.z + a2.x * w0.z + a2.y * w1.z + a2.z * w2.z + a2.w * w3.z;
            float q3 = vl2.w + vr.w + a2.x * w0.w + a2.y * w1.w + a2.z * w2.w + a2.w * w3.w;
            q0 = (q0 > 0.f) ? q0 : NEG * q0; q1 = (q1 > 0.f) ? q1 : NEG * q1;
            q2 = (q2 > 0.f) ? q2 : NEG * q2; q3 = (q3 > 0.f) ? q3 : NEG * q3;
            p2 = q0 * av.x + q1 * av.y + q2 * av.z + q3 * av.w;
        }
        {
            float q0 = vl3.x + vr.x + a3.x * w0.x + a3.y * w1.x + a3.z * w2.x + a3.w * w3.x;
            float q1 = vl3.y + vr.y + a3.x * w0.y + a3.y * w1.y + a3.z * w2.y + a3.w * w3.y;
            float q2 = vl3.z + vr.z + a3.x * w0.z + a3.y * w1.z + a3.z * w2.z + a3.w * w3.z;
            float q3 = vl3.w + vr.w + a3.x * w0.w + a3.y * w1.w + a3.z * w2.w + a3.w * w3.w;
            q0 = (q0 > 0.f) ? q0 : NEG * q0; q1 = (q1 > 0.f) ? q1 : NEG * q1;
            q2 = (q2 > 0.f) ? q2 : NEG * q2; q3 = (q3 > 0.f) ? q3 : NEG * q3;
            p3 = q0 * av.x + q1 * av.y + q2 * av.z + q3 * av.w;
        }
#pragma unroll
        for (int off = 1; off <= 8; off <<= 1) {
            p0 += __shfl_xor(p0, off, 64);
            p1 += __shfl_xor(p1, off, 64);
            p2 += __shfl_xor(p2, off, 64);
            p3 += __shfl_xor(p3, off, 64);
        }
        // mask pad slots to -inf -> exp()=0, softmax unchanged
        p0 = (s0 < 0) ? -INFINITY : p0;
        p1 = (s1 < 0) ? -INFINITY : p1;
        p2 = (s2 < 0) ? -INFINITY : p2;
        p3 = (s3 < 0) ? -INFINITY : p3;
        float pm = fmaxf(fmaxf(p0, p1), fmaxf(p2, p3));
        float newm = fmaxf(m, pm);
        float so = expf(m - newm);
        float e0 = expf(p0 - newm);
        float e1 = expf(p1 - newm);
        float e2 = expf(p2 - newm);
        float e3 = expf(p3 - newm);
        denom = denom * so + e0 + e1 + e2 + e3;
        ax = ax * so + e0 * vl0.x + e1 * vl1.x + e2 * vl2.x + e3 * vl3.x;
        ay = ay * so + e0 * vl0.y + e1 * vl1.y + e2 * vl2.y + e3 * vl3.y;
        az = az * so + e0 * vl0.z + e1 * vl1.z + e2 * vl2.z + e3 * vl3.z;
        aw = aw * so + e0 * vl0.w + e1 * vl1.w + e2 * vl2.w + e3 * vl3.w;
        m = newm;
    }
    float inv = 0.25f / (denom + 1e-16f);   // head-mean folded in
    ax *= inv; ay *= inv; az *= inv; aw *= inv;
    ax += __shfl_xor(ax, 16, 64); ax += __shfl_xor(ax, 32, 64);
    ay += __shfl_xor(ay, 16, 64); ay += __shfl_xor(ay, 32, 64);
    az += __shfl_xor(az, 16, 64); az += __shfl_xor(az, 32, 64);
    aw += __shfl_xor(aw, 16, 64); aw += __shfl_xor(aw, 32, 64);
    if (lane < 16) {
        float4 b = *(const float4*)&bias[c4];
        float4 o;
        o.x = fmaxf(ax + b.x, 0.f);
        o.y = fmaxf(ay + b.y, 0.f);
        o.z = fmaxf(az + b.z, 0.f);
        o.w = fmaxf(aw + b.w, 0.f);
        *(float4*)&hout[(size_t)d * HID + c4] = o;
    }
}

// ---- pooling: chunked segment sum (batch is sorted) ----
__global__ __launch_bounds__(256) void pool_k(
    const float* __restrict__ h, const int* __restrict__ batch,
    float* __restrict__ pooled)
{
    constexpr int CH = 16;
    int c = threadIdx.x & 63;
    int chunk = blockIdx.x * 4 + (threadIdx.x >> 6);
    int n0 = chunk * CH;
    if (n0 >= N) return;
    int nend = (n0 + CH < N) ? n0 + CH : N;
    float sum = 0.f;
    int curb = batch[n0];
    for (int n = n0; n < nend; ++n) {
        int b = batch[n];
        if (b != curb) {
            atomicAdd(&pooled[curb * HID + c], sum);
            sum = 0.f; curb = b;
        }
        sum += h[(size_t)n * HID + c];
    }
    atomicAdd(&pooled[curb * HID + c], sum);
}

// ---- MLP head: one block (64 threads) per graph ----
__global__ __launch_bounds__(64) void head_k(
    const float* __restrict__ pooled, const int* __restrict__ batch,
    const float* __restrict__ W_fc, const float* __restrict__ b_fc,
    const float* __restrict__ W_res, const float* __restrict__ b_res,
    const float* __restrict__ W_time, const float* __restrict__ b_time,
    float* __restrict__ out)
{
    int g = blockIdx.x;
    int c = threadIdx.x;
    int lo = 0, hi = N;
    while (lo < hi) { int mid = (lo + hi) >> 1; if (batch[mid] < g) lo = mid + 1; else hi = mid; }
    int start = lo;
    hi = N;
    while (lo < hi) { int mid = (lo + hi) >> 1; if (batch[mid] < g + 1) lo = mid + 1; else hi = mid; }
    int end = lo;
    float cnt = (float)(end - start);
    float p = pooled[g * HID + c] / fmaxf(cnt, 1.0f);
    __shared__ float ps[HID];
    ps[c] = p;
    __syncthreads();
    float gv = b_fc[c];
    for (int k = 0; k < HID; k++) gv += ps[k] * W_fc[k * HID + c];
    gv = fmaxf(gv, 0.f);
    float r = gv * W_res[c];
    float t = gv * W_time[c];
#pragma unroll
    for (int off = 32; off > 0; off >>= 1) {
        r += __shfl_down(r, off, 64);
        t += __shfl_down(t, off, 64);
    }
    if (c == 0) {
        out[g * 2 + 0] = r + b_res[0];
        out[g * 2 + 1] = t + b_time[0];
    }
}

} // namespace

extern "C" void kernel_launch(void* const* d_in, const int* in_sizes, int n_in,
                              void* d_out, int out_size, void* d_ws, size_t ws_size,
                              hipStream_t stream) {
    const float* x         = (const float*)d_in[0];
    const float* edge_attr = (const float*)d_in[1];
    const int*   edge_index= (const int*)d_in[2];
    const int*   batch     = (const int*)d_in[3];
    const float* W_et = (const float*)d_in[4];
    const float* b_et = (const float*)d_in[5];
    const float* W_uw = (const float*)d_in[6];
    const float* b_uw = (const float*)d_in[7];
    const float* W_ua = (const float*)d_in[8];
    const float* b_ua = (const float*)d_in[9];
    const float* Wl0  = (const float*)d_in[10];
    const float* bl0  = (const float*)d_in[11];
    const float* Wr0  = (const float*)d_in[12];
    const float* br0  = (const float*)d_in[13];
    const float* att0 = (const float*)d_in[14];
    const float* We0  = (const float*)d_in[15];
    const float* bias0= (const float*)d_in[16];
    const float* Wl1  = (const float*)d_in[17];
    const float* bl1  = (const float*)d_in[18];
    const float* Wr1  = (const float*)d_in[19];
    const float* br1  = (const float*)d_in[20];
    const float* att1 = (const float*)d_in[21];
    const float* We1  = (const float*)d_in[22];
    const float* bias1= (const float*)d_in[23];
    const float* W_fc = (const float*)d_in[24];
    const float* b_fc = (const float*)d_in[25];
    const float* W_res= (const float*)d_in[26];
    const float* b_res= (const float*)d_in[27];
    const float* W_time=(const float*)d_in[28];
    const float* b_time=(const float*)d_in[29];

    const int* src = edge_index;     // row 0
    const int* dst = edge_index + E; // row 1

    // workspace layout (16B aligned segments)
    float* ws    = (float*)d_ws;
    float* xl    = ws;                        // N*HH
    float* xr    = xl  + (size_t)N * HH;      // N*HH
    float* h1    = xr  + (size_t)N * HH;      // N*HID
    float* h2    = h1  + (size_t)N * HID;     // N*HID
    float* pooled= h2  + (size_t)N * HID;     // G*HID
    int*   deg      = (int*)(pooled + (size_t)G * HID); // N (adjacent to pooled)
    int*   row_start= deg + N;                // N
    int*   bsum     = row_start + N;          // 256
    int*   rank     = bsum + 256;             // E
    int*   csr_src  = rank + E;               // EP
    float* eap_csr  = (float*)(csr_src + EP); // EP*4

    dim3 b256(256);
    const int NB = (N + 255) / 256; // 196

    // pooled = 0, deg = 0 (adjacent, one memset); csr_src = -1 (pad sentinel)
    hipMemsetAsync(pooled, 0, (size_t)(G * HID + N) * 4, stream);
    hipMemsetAsync(csr_src, 0xFF, (size_t)EP * 4, stream);
    // CSR build (rank-based, padded rows)
    hist_k<<<(E + 255) / 256, b256, 0, stream>>>(dst, deg, rank);
    scan1_k<<<NB, b256, 0, stream>>>(deg, row_start, bsum);
    scan2_k<<<1, b256, 0, stream>>>(bsum, NB);
    scan3_k<<<NB, b256, 0, stream>>>(row_start, bsum);
    scatter_k<<<(E + 255) / 256, b256, 0, stream>>>(
        src, dst, edge_attr, W_et, b_et, W_uw, b_uw, W_ua, b_ua,
        row_start, rank, csr_src, eap_csr);

    dim3 proj_grid((N + 31) / 32, 2);

    // ---------- layer 0 ----------
    proj_k<128><<<proj_grid, b256, 0, stream>>>(x, Wl0, bl0, Wr0, br0, xl, xr);
    gat_aggr_k<<<(N + 3) / 4, b256, 0, stream>>>(
        xl, xr, eap_csr, We0, att0, row_start, deg, csr_src, bias0, h1);

    // ---------- layer 1 ----------
    proj_k<64><<<proj_grid, b256, 0, stream>>>(h1, Wl1, bl1, Wr1, br1, xl, xr);
    gat_aggr_k<<<(N + 3) / 4, b256, 0, stream>>>(
        xl, xr, eap_csr, We1, att1, row_start, deg, csr_src, bias1, h2);

    // ---------- pooling + head ----------
    pool_k<<<((N + 15) / 16 + 3) / 4, b256, 0, stream>>>(h2, batch, pooled);
    head_k<<<G, dim3(64), 0, stream>>>(
        pooled, batch, W_fc, b_fc, W_res, b_res, W_time, b_time, (float*)d_out);
}

// Round 14
// 463.720 us; speedup vs baseline: 1.1584x; 1.0819x over previous
//
#include <hip/hip_runtime.h>
#include <math.h>

namespace {

constexpr int N = 50000;
constexpr int E = 400000;
constexpr int G = 64;
constexpr int HID = 64;
constexpr int HH = 256; // NHEAD*HID
constexpr float NEG = 0.2f;

// ---- degree histogram + per-edge rank (deg pre-zeroed by memset) ----
__global__ __launch_bounds__(256) void hist_k(
    const int* __restrict__ dst, int* __restrict__ deg, int* __restrict__ rank)
{
    int e = blockIdx.x * 256 + threadIdx.x;
    if (e < E) rank[e] = atomicAdd(&deg[dst[e]], 1);
}

// block-local exclusive prefix of deg -> pre; per-block totals -> bsum
__global__ __launch_bounds__(256) void scan1_k(
    const int* __restrict__ deg, int* __restrict__ pre, int* __restrict__ bsum)
{
    __shared__ int s[256];
    int i = blockIdx.x * 256 + threadIdx.x;
    int v = (i < N) ? deg[i] : 0;
    s[threadIdx.x] = v;
    __syncthreads();
    for (int off = 1; off < 256; off <<= 1) {
        int t = (threadIdx.x >= off) ? s[threadIdx.x - off] : 0;
        __syncthreads();
        s[threadIdx.x] += t;
        __syncthreads();
    }
    if (i < N) pre[i] = s[threadIdx.x] - v;
    if (threadIdx.x == 255) bsum[blockIdx.x] = s[255];
}

// exclusive prefix over block totals (in place)
__global__ __launch_bounds__(256) void scan2_k(int* __restrict__ bsum, int nb)
{
    __shared__ int s[256];
    int tid = threadIdx.x;
    int v = (tid < nb) ? bsum[tid] : 0;
    s[tid] = v;
    __syncthreads();
    for (int off = 1; off < 256; off <<= 1) {
        int t = (tid >= off) ? s[tid - off] : 0;
        __syncthreads();
        s[tid] += t;
        __syncthreads();
    }
    if (tid < nb) bsum[tid] = s[tid] - v;
}

// ---- scatter edges to CSR order (no atomics); compute eap on the fly ----
// row_start[v] = pre[v] + bsum[v>>8], computed inline (scan3 eliminated)
__global__ __launch_bounds__(256) void scatter_k(
    const int* __restrict__ src, const int* __restrict__ dst,
    const float* __restrict__ ea,
    const float* __restrict__ W_et, const float* __restrict__ b_et,
    const float* __restrict__ W_uw, const float* __restrict__ b_uw,
    const float* __restrict__ W_ua, const float* __restrict__ b_ua,
    const int* __restrict__ pre, const int* __restrict__ bsum,
    const int* __restrict__ rank,
    int* __restrict__ csr_src, float* __restrict__ eap_csr)
{
    int e = blockIdx.x * 256 + threadIdx.x;
    if (e >= E) return;
    float et = ea[e * 2 + 0], uw = ea[e * 2 + 1];
    float ua = 1.f / (1.f + expf(-(uw * W_ua[0] + b_ua[0])));
    float4 v;
    v.x = et * W_et[0] + b_et[0];
    v.y = et * W_et[1] + b_et[1];
    v.z = (uw * W_uw[0] + b_uw[0]) * ua;
    v.w = (uw * W_uw[1] + b_uw[1]) * ua;
    int d = dst[e];
    int pos = pre[d] + bsum[d >> 8] + rank[e];
    csr_src[pos] = src[e];
    *(float4*)&eap_csr[(size_t)pos * 4] = v;
}

// ---- node projection (best known): 32 nodes/block LDS, 4 cols x 8 nodes ----
template <int IC>
__global__ __launch_bounds__(256) void proj_k(
    const float* __restrict__ x,
    const float* __restrict__ Wl, const float* __restrict__ bl,
    const float* __restrict__ Wr, const float* __restrict__ br,
    float* __restrict__ xl, float* __restrict__ xr)
{
    constexpr int NPB = 32;
    __shared__ float xs[NPB][IC];
    const float* __restrict__ W  = blockIdx.y ? Wr : Wl;
    const float* __restrict__ bp = blockIdx.y ? br : bl;
    float* __restrict__ out      = blockIdx.y ? xr : xl;
    const int base = blockIdx.x * NPB;
    const int tid = threadIdx.x;
    for (int idx = tid; idx < NPB * IC / 4; idx += 256) {
        int j = idx / (IC / 4), k4 = idx - j * (IC / 4);
        int n = base + j;
        float4 v = make_float4(0.f, 0.f, 0.f, 0.f);
        if (n < N) v = *(const float4*)&x[(size_t)n * IC + k4 * 4];
        *(float4*)&xs[j][k4 * 4] = v;
    }
    __syncthreads();
    const int col4 = (tid & 63) * 4;
    const int jg = (tid >> 6) * 8;   // 8 nodes per thread
    float4 acc[8];
#pragma unroll
    for (int j = 0; j < 8; j++) acc[j] = make_float4(0.f, 0.f, 0.f, 0.f);
    for (int k = 0; k < IC; k += 4) {
        float4 w0 = *(const float4*)&W[(size_t)(k + 0) * HH + col4];
        float4 w1 = *(const float4*)&W[(size_t)(k + 1) * HH + col4];
        float4 w2 = *(const float4*)&W[(size_t)(k + 2) * HH + col4];
        float4 w3 = *(const float4*)&W[(size_t)(k + 3) * HH + col4];
#pragma unroll
        for (int j = 0; j < 8; j++) {
            float4 xv = *(const float4*)&xs[jg + j][k];
            acc[j].x += xv.x * w0.x + xv.y * w1.x + xv.z * w2.x + xv.w * w3.x;
            acc[j].y += xv.x * w0.y + xv.y * w1.y + xv.z * w2.y + xv.w * w3.y;
            acc[j].z += xv.x * w0.z + xv.y * w1.z + xv.z * w2.z + xv.w * w3.z;
            acc[j].w += xv.x * w0.w + xv.y * w1.w + xv.z * w2.w + xv.w * w3.w;
        }
    }
    float4 bb = *(const float4*)&bp[col4];
#pragma unroll
    for (int j = 0; j < 8; j++) {
        int n = base + jg + j;
        if (n < N) {
            float4 o;
            o.x = acc[j].x + bb.x;
            o.y = acc[j].y + bb.y;
            o.z = acc[j].z + bb.z;
            o.w = acc[j].w + bb.w;
            *(float4*)&out[(size_t)n * HH + col4] = o;
        }
    }
}

// ---- fused GAT layer (best known): unroll-4 + tail, online softmax ----
// one 64-lane wave per dst node; lane l covers cols 4l..4l+3 (head = l>>4)
__global__ __launch_bounds__(256) void gat_aggr_k(
    const float* __restrict__ xl, const float* __restrict__ xr,
    const float* __restrict__ eap_csr, const float* __restrict__ We,
    const float* __restrict__ att,
    const int* __restrict__ pre, const int* __restrict__ bsum,
    const int* __restrict__ deg,
    const int* __restrict__ csr_src,
    const float* __restrict__ bias, float* __restrict__ hout)
{
    int d = blockIdx.x * 4 + (threadIdx.x >> 6);
    int lane = threadIdx.x & 63;
    if (d >= N) return;
    int c4 = lane * 4;
    const float4 w0 = *(const float4*)&We[0 * HH + c4];
    const float4 w1 = *(const float4*)&We[1 * HH + c4];
    const float4 w2 = *(const float4*)&We[2 * HH + c4];
    const float4 w3 = *(const float4*)&We[3 * HH + c4];
    const float4 av = *(const float4*)&att[c4];
    const float4 vr = *(const float4*)&xr[(size_t)d * HH + c4];
    int start = pre[d] + bsum[d >> 8];
    int end = start + deg[d];
    float m = -INFINITY, denom = 0.f;
    float ax = 0.f, ay = 0.f, az = 0.f, aw = 0.f;
    int idx = start;
    for (; idx + 4 <= end; idx += 4) {
        int s0 = csr_src[idx], s1 = csr_src[idx + 1];
        int s2 = csr_src[idx + 2], s3 = csr_src[idx + 3];
        float4 a0 = *(const float4*)&eap_csr[(size_t)(idx + 0) * 4];
        float4 a1 = *(const float4*)&eap_csr[(size_t)(idx + 1) * 4];
        float4 a2 = *(const float4*)&eap_csr[(size_t)(idx + 2) * 4];
        float4 a3 = *(const float4*)&eap_csr[(size_t)(idx + 3) * 4];
        float4 vl0 = *(const float4*)&xl[(size_t)s0 * HH + c4];
        float4 vl1 = *(const float4*)&xl[(size_t)s1 * HH + c4];
        float4 vl2 = *(const float4*)&xl[(size_t)s2 * HH + c4];
        float4 vl3 = *(const float4*)&xl[(size_t)s3 * HH + c4];
        float p0, p1, p2, p3;
        {
            float q0 = vl0.x + vr.x + a0.x * w0.x + a0.y * w1.x + a0.z * w2.x + a0.w * w3.x;
            float q1 = vl0.y + vr.y + a0.x * w0.y + a0.y * w1.y + a0.z * w2.y + a0.w * w3.y;
            float q2 = vl0.z + vr.z + a0.x * w0.z + a0.y * w1.z + a0.z * w2.z + a0.w * w3.z;
            float q3 = vl0.w + vr.w + a0.x * w0.w + a0.y * w1.w + a0.z * w2.w + a0.w * w3.w;
            q0 = (q0 > 0.f) ? q0 : NEG * q0; q1 = (q1 > 0.f) ? q1 : NEG * q1;
            q2 = (q2 > 0.f) ? q2 : NEG * q2; q3 = (q3 > 0.f) ? q3 : NEG * q3;
            p0 = q0 * av.x + q1 * av.y + q2 * av.z + q3 * av.w;
        }
        {
            float q0 = vl1.x + vr.x + a1.x * w0.x + a1.y * w1.x + a1.z * w2.x + a1.w * w3.x;
            float q1 = vl1.y + vr.y + a1.x * w0.y + a1.y * w1.y + a1.z * w2.y + a1.w * w3.y;
            float q2 = vl1.z + vr.z + a1.x * w0.z + a1.y * w1.z + a1.z * w2.z + a1.w * w3.z;
            float q3 = vl1.w + vr.w + a1.x * w0.w + a1.y * w1.w + a1.z * w2.w + a1.w * w3.w;
            q0 = (q0 > 0.f) ? q0 : NEG * q0; q1 = (q1 > 0.f) ? q1 : NEG * q1;
            q2 = (q2 > 0.f) ? q2 : NEG * q2; q3 = (q3 > 0.f) ? q3 : NEG * q3;
            p1 = q0 * av.x + q1 * av.y + q2 * av.z + q3 * av.w;
        }
        {
            float q0 = vl2.x + vr.x + a2.x * w0.x + a2.y * w1.x + a2.z * w2.x + a2.w * w3.x;
            float q1 = vl2.y + vr.y + a2.x * w0.y + a2.y * w1.y + a2.z * w2.y + a2.w * w3.y;
            float q2 = vl2.z + vr.z + a2.x * w0.z + a2.y * w1.z + a2.z * w2.z + a2.w * w3.z;
            float q3 = vl2.w + vr.w + a2.x * w0.w + a2.y * w1.w + a2.z * w2.w + a2.w * w3.w;
            q0 = (q0 > 0.f) ? q0 : NEG * q0; q1 = (q1 > 0.f) ? q1 : NEG * q1;
            q2 = (q2 > 0.f) ? q2 : NEG * q2; q3 = (q3 > 0.f) ? q3 : NEG * q3;
            p2 = q0 * av.x + q1 * av.y + q2 * av.z + q3 * av.w;
        }
        {
            float q0 = vl3.x + vr.x + a3.x * w0.x + a3.y * w1.x + a3.z * w2.x + a3.w * w3.x;
            float q1 = vl3.y + vr.y + a3.x * w0.y + a3.y * w1.y + a3.z * w2.y + a3.w * w3.y;
            float q2 = vl3.z + vr.z + a3.x * w0.z + a3.y * w1.z + a3.z * w2.z + a3.w * w3.z;
            float q3 = vl3.w + vr.w + a3.x * w0.w + a3.y * w1.w + a3.z * w2.w + a3.w * w3.w;
            q0 = (q0 > 0.f) ? q0 : NEG * q0; q1 = (q1 > 0.f) ? q1 : NEG * q1;
            q2 = (q2 > 0.f) ? q2 : NEG * q2; q3 = (q3 > 0.f) ? q3 : NEG * q3;
            p3 = q0 * av.x + q1 * av.y + q2 * av.z + q3 * av.w;
        }
#pragma unroll
        for (int off = 1; off <= 8; off <<= 1) {
            p0 += __shfl_xor(p0, off, 64);
            p1 += __shfl_xor(p1, off, 64);
            p2 += __shfl_xor(p2, off, 64);
            p3 += __shfl_xor(p3, off, 64);
        }
        float pm = fmaxf(fmaxf(p0, p1), fmaxf(p2, p3));
        float newm = fmaxf(m, pm);
        float so = expf(m - newm);
        float e0 = expf(p0 - newm);
        float e1 = expf(p1 - newm);
        float e2 = expf(p2 - newm);
        float e3 = expf(p3 - newm);
        denom = denom * so + e0 + e1 + e2 + e3;
        ax = ax * so + e0 * vl0.x + e1 * vl1.x + e2 * vl2.x + e3 * vl3.x;
        ay = ay * so + e0 * vl0.y + e1 * vl1.y + e2 * vl2.y + e3 * vl3.y;
        az = az * so + e0 * vl0.z + e1 * vl1.z + e2 * vl2.z + e3 * vl3.z;
        aw = aw * so + e0 * vl0.w + e1 * vl1.w + e2 * vl2.w + e3 * vl3.w;
        m = newm;
    }
    for (; idx < end; ++idx) {
        int s = csr_src[idx];
        float4 a = *(const float4*)&eap_csr[(size_t)idx * 4];
        float4 vl = *(const float4*)&xl[(size_t)s * HH + c4];
        float q0 = vl.x + vr.x + a.x * w0.x + a.y * w1.x + a.z * w2.x + a.w * w3.x;
        float q1 = vl.y + vr.y + a.x * w0.y + a.y * w1.y + a.z * w2.y + a.w * w3.y;
        float q2 = vl.z + vr.z + a.x * w0.z + a.y * w1.z + a.z * w2.z + a.w * w3.z;
        float q3 = vl.w + vr.w + a.x * w0.w + a.y * w1.w + a.z * w2.w + a.w * w3.w;
        q0 = (q0 > 0.f) ? q0 : NEG * q0; q1 = (q1 > 0.f) ? q1 : NEG * q1;
        q2 = (q2 > 0.f) ? q2 : NEG * q2; q3 = (q3 > 0.f) ? q3 : NEG * q3;
        float p = q0 * av.x + q1 * av.y + q2 * av.z + q3 * av.w;
#pragma unroll
        for (int off = 1; off <= 8; off <<= 1) p += __shfl_xor(p, off, 64);
        float newm = fmaxf(m, p);
        float so = expf(m - newm);
        float ex = expf(p - newm);
        denom = denom * so + ex;
        ax = ax * so + ex * vl.x;
        ay = ay * so + ex * vl.y;
        az = az * so + ex * vl.z;
        aw = aw * so + ex * vl.w;
        m = newm;
    }
    float inv = 0.25f / (denom + 1e-16f);   // head-mean folded in
    ax *= inv; ay *= inv; az *= inv; aw *= inv;
    ax += __shfl_xor(ax, 16, 64); ax += __shfl_xor(ax, 32, 64);
    ay += __shfl_xor(ay, 16, 64); ay += __shfl_xor(ay, 32, 64);
    az += __shfl_xor(az, 16, 64); az += __shfl_xor(az, 32, 64);
    aw += __shfl_xor(aw, 16, 64); aw += __shfl_xor(aw, 32, 64);
    if (lane < 16) {
        float4 b = *(const float4*)&bias[c4];
        float4 o;
        o.x = fmaxf(ax + b.x, 0.f);
        o.y = fmaxf(ay + b.y, 0.f);
        o.z = fmaxf(az + b.z, 0.f);
        o.w = fmaxf(aw + b.w, 0.f);
        *(float4*)&hout[(size_t)d * HID + c4] = o;
    }
}

// ---- pooling: chunked segment sum (batch is sorted) ----
__global__ __launch_bounds__(256) void pool_k(
    const float* __restrict__ h, const int* __restrict__ batch,
    float* __restrict__ pooled)
{
    constexpr int CH = 16;
    int c = threadIdx.x & 63;
    int chunk = blockIdx.x * 4 + (threadIdx.x >> 6);
    int n0 = chunk * CH;
    if (n0 >= N) return;
    int nend = (n0 + CH < N) ? n0 + CH : N;
    float sum = 0.f;
    int curb = batch[n0];
    for (int n = n0; n < nend; ++n) {
        int b = batch[n];
        if (b != curb) {
            atomicAdd(&pooled[curb * HID + c], sum);
            sum = 0.f; curb = b;
        }
        sum += h[(size_t)n * HID + c];
    }
    atomicAdd(&pooled[curb * HID + c], sum);
}

// ---- MLP head: one block (64 threads) per graph ----
__global__ __launch_bounds__(64) void head_k(
    const float* __restrict__ pooled, const int* __restrict__ batch,
    const float* __restrict__ W_fc, const float* __restrict__ b_fc,
    const float* __restrict__ W_res, const float* __restrict__ b_res,
    const float* __restrict__ W_time, const float* __restrict__ b_time,
    float* __restrict__ out)
{
    int g = blockIdx.x;
    int c = threadIdx.x;
    int lo = 0, hi = N;
    while (lo < hi) { int mid = (lo + hi) >> 1; if (batch[mid] < g) lo = mid + 1; else hi = mid; }
    int start = lo;
    hi = N;
    while (lo < hi) { int mid = (lo + hi) >> 1; if (batch[mid] < g + 1) lo = mid + 1; else hi = mid; }
    int end = lo;
    float cnt = (float)(end - start);
    float p = pooled[g * HID + c] / fmaxf(cnt, 1.0f);
    __shared__ float ps[HID];
    ps[c] = p;
    __syncthreads();
    float gv = b_fc[c];
    for (int k = 0; k < HID; k++) gv += ps[k] * W_fc[k * HID + c];
    gv = fmaxf(gv, 0.f);
    float r = gv * W_res[c];
    float t = gv * W_time[c];
#pragma unroll
    for (int off = 32; off > 0; off >>= 1) {
        r += __shfl_down(r, off, 64);
        t += __shfl_down(t, off, 64);
    }
    if (c == 0) {
        out[g * 2 + 0] = r + b_res[0];
        out[g * 2 + 1] = t + b_time[0];
    }
}

} // namespace

extern "C" void kernel_launch(void* const* d_in, const int* in_sizes, int n_in,
                              void* d_out, int out_size, void* d_ws, size_t ws_size,
                              hipStream_t stream) {
    const float* x         = (const float*)d_in[0];
    const float* edge_attr = (const float*)d_in[1];
    const int*   edge_index= (const int*)d_in[2];
    const int*   batch     = (const int*)d_in[3];
    const float* W_et = (const float*)d_in[4];
    const float* b_et = (const float*)d_in[5];
    const float* W_uw = (const float*)d_in[6];
    const float* b_uw = (const float*)d_in[7];
    const float* W_ua = (const float*)d_in[8];
    const float* b_ua = (const float*)d_in[9];
    const float* Wl0  = (const float*)d_in[10];
    const float* bl0  = (const float*)d_in[11];
    const float* Wr0  = (const float*)d_in[12];
    const float* br0  = (const float*)d_in[13];
    const float* att0 = (const float*)d_in[14];
    const float* We0  = (const float*)d_in[15];
    const float* bias0= (const float*)d_in[16];
    const float* Wl1  = (const float*)d_in[17];
    const float* bl1  = (const float*)d_in[18];
    const float* Wr1  = (const float*)d_in[19];
    const float* br1  = (const float*)d_in[20];
    const float* att1 = (const float*)d_in[21];
    const float* We1  = (const float*)d_in[22];
    const float* bias1= (const float*)d_in[23];
    const float* W_fc = (const float*)d_in[24];
    const float* b_fc = (const float*)d_in[25];
    const float* W_res= (const float*)d_in[26];
    const float* b_res= (const float*)d_in[27];
    const float* W_time=(const float*)d_in[28];
    const float* b_time=(const float*)d_in[29];

    const int* src = edge_index;     // row 0
    const int* dst = edge_index + E; // row 1

    // workspace layout (16B aligned segments)
    float* ws    = (float*)d_ws;
    float* xl    = ws;                        // N*HH
    float* xr    = xl  + (size_t)N * HH;      // N*HH
    float* h1    = xr  + (size_t)N * HH;      // N*HID
    float* h2    = h1  + (size_t)N * HID;     // N*HID
    float* pooled= h2  + (size_t)N * HID;     // G*HID
    int*   deg      = (int*)(pooled + (size_t)G * HID); // N (adjacent to pooled)
    int*   pre      = deg + N;                // N (block-local exclusive prefix)
    int*   bsum     = pre + N;                // 256
    int*   rank     = bsum + 256;             // E
    int*   csr_src  = rank + E;               // E
    float* eap_csr  = (float*)(csr_src + E);  // E*4

    dim3 b256(256);
    const int NB = (N + 255) / 256; // 196

    // zero pooled + deg in one memset (adjacent in layout)
    hipMemsetAsync(pooled, 0, (size_t)(G * HID + N) * 4, stream);
    // CSR build (rank-based, no scatter atomics, scan3 folded into consumers)
    hist_k<<<(E + 255) / 256, b256, 0, stream>>>(dst, deg, rank);
    scan1_k<<<NB, b256, 0, stream>>>(deg, pre, bsum);
    scan2_k<<<1, b256, 0, stream>>>(bsum, NB);
    scatter_k<<<(E + 255) / 256, b256, 0, stream>>>(
        src, dst, edge_attr, W_et, b_et, W_uw, b_uw, W_ua, b_ua,
        pre, bsum, rank, csr_src, eap_csr);

    dim3 proj_grid((N + 31) / 32, 2);

    // ---------- layer 0 ----------
    proj_k<128><<<proj_grid, b256, 0, stream>>>(x, Wl0, bl0, Wr0, br0, xl, xr);
    gat_aggr_k<<<(N + 3) / 4, b256, 0, stream>>>(
        xl, xr, eap_csr, We0, att0, pre, bsum, deg, csr_src, bias0, h1);

    // ---------- layer 1 ----------
    proj_k<64><<<proj_grid, b256, 0, stream>>>(h1, Wl1, bl1, Wr1, br1, xl, xr);
    gat_aggr_k<<<(N + 3) / 4, b256, 0, stream>>>(
        xl, xr, eap_csr, We1, att1, pre, bsum, deg, csr_src, bias1, h2);

    // ---------- pooling + head ----------
    pool_k<<<((N + 15) / 16 + 3) / 4, b256, 0, stream>>>(h2, batch, pooled);
    head_k<<<G, dim3(64), 0, stream>>>(
        pooled, batch, W_fc, b_fc, W_res, b_res, W_time, b_time, (float*)d_out);
}